// Round 10
// baseline (120.213 us; speedup 1.0000x reference)
//
#include <hip/hip_runtime.h>

// Trilinear table lookup: (x, y/4)-bin counting sort -> per-bin LDS-staged,
// pair-cooperative (shuffle-free) gather.
//
// unList: [B,3] f32 in [0,1]; table: [128,128,128,8] f32; out: [B,8] f32
//
// R9 evidence: 22.5 cy/pt == the per-pass latency chain (ds_read ~120cy +
// bpermute ~120cy per 16 pts). Fix: 2 lanes/point, each lane reads all 8
// corner-cell halves via ONE base addr + immediate offsets (8 ds_read_b128,
// no shuffle), 32 pts/wave-pass -> ~8 cy/pt chain.

#define DIM 128
#define CH 8
#define NBIN 4064            // 127 x-cells * 32 y-groups (y0>>2)
#define TBYTES 67108864u     // 128^3 * 8 * 4
#define CHUNK 8192
#define PPT 32
// ws layout (bytes):
//   [0,     16384)  hist   (u32 x 4064, zeroed each call)
//   [16384, 32768)  cursor (u32 x 4064, rewritten by k_scan)
//   [32768, 49152)  base   (u32 x 4065, rewritten by k_scan)
//   [65536, ...  )  rec    (float4 x B : x,y,z,bits(orig))
#define CUR_OFF 16384
#define BASE_OFF 32768
#define REC_OFF 65536

__device__ __forceinline__ int key_of(float ux, float uy) {
    float sx = fminf(fmaxf(ux, 0.0f), 1.0f) * 127.0f;
    float sy = fminf(fmaxf(uy, 0.0f), 1.0f) * 127.0f;
    int x0 = (int)fminf(floorf(sx), 126.0f);
    int y0 = (int)fminf(floorf(sy), 126.0f);
    return x0 * 32 + (y0 >> 2);
}

__global__ __launch_bounds__(256) void k_hist(const float* __restrict__ un,
                                              unsigned* __restrict__ hist, int batch) {
    __shared__ unsigned lh[NBIN];
    for (int i = threadIdx.x; i < NBIN; i += 256) lh[i] = 0;
    __syncthreads();
    int stride = gridDim.x * blockDim.x;
    for (int i = blockIdx.x * blockDim.x + threadIdx.x; i < batch; i += stride)
        atomicAdd(&lh[key_of(un[3 * i], un[3 * i + 1])], 1u);
    __syncthreads();
    for (int i = threadIdx.x; i < NBIN; i += 256)
        if (lh[i]) atomicAdd(&hist[i], lh[i]);
}

// exclusive scan of 4064 bins -> cursor & base (+ base[NBIN] = total)
__global__ __launch_bounds__(1024) void k_scan(const unsigned* __restrict__ hist,
                                               unsigned* __restrict__ cursor,
                                               unsigned* __restrict__ base) {
    __shared__ unsigned s[1024];
    int t = threadIdx.x;
    int b0 = t * 4;
    unsigned loc[4], sum = 0;
#pragma unroll
    for (int j = 0; j < 4; ++j) {
        int k = b0 + j;
        unsigned h = (k < NBIN) ? hist[k] : 0u;
        loc[j] = sum;
        sum += h;
    }
    s[t] = sum;
    __syncthreads();
    for (int off = 1; off < 1024; off <<= 1) {
        unsigned v = (t >= off) ? s[t - off] : 0u;
        __syncthreads();
        s[t] += v;
        __syncthreads();
    }
    unsigned excl = s[t] - sum;
#pragma unroll
    for (int j = 0; j < 4; ++j) {
        int k = b0 + j;
        if (k < NBIN) { base[k] = excl + loc[j]; cursor[k] = excl + loc[j]; }
    }
    if (t == 1023) base[NBIN] = s[1023];
}

__global__ __launch_bounds__(256) void k_scatter(const float* __restrict__ un,
                                                 unsigned* __restrict__ cursor,
                                                 float4* __restrict__ rec, int batch) {
    __shared__ unsigned lh[NBIN];
    __shared__ unsigned lbase[NBIN];
    int t = threadIdx.x;
    for (int i = t; i < NBIN; i += 256) lh[i] = 0;
    __syncthreads();
    int start = blockIdx.x * CHUNK;
    unsigned kr[PPT];
#pragma unroll
    for (int j = 0; j < PPT; ++j) {
        int i = start + j * 256 + t;
        if (i < batch) {
            int k = key_of(un[3 * i], un[3 * i + 1]);
            unsigned r = atomicAdd(&lh[k], 1u);
            kr[j] = (unsigned)k | (r << 12);
        } else kr[j] = 0u;
    }
    __syncthreads();
    for (int i = t; i < NBIN; i += 256)
        lbase[i] = lh[i] ? atomicAdd(&cursor[i], lh[i]) : 0u;
    __syncthreads();
#pragma unroll
    for (int j = 0; j < PPT; ++j) {
        int i = start + j * 256 + t;
        if (i < batch) {
            unsigned k = kr[j] & 4095u, r = kr[j] >> 12;
            float ux = un[3 * i], uy = un[3 * i + 1], uz = un[3 * i + 2];
            rec[lbase[k] + r] = make_float4(ux, uy, uz, __uint_as_float((unsigned)i));
        }
    }
}

// One block per bin. Stage 40 KB (x-planes x0/x0+1, rows ybase..ybase+4) into
// LDS via global_load_lds DMA, then pair-cooperative gather:
// lane pair (2p, 2p+1) owns point p of the pass; lane h = lane&1 reads all
// 8 corner-cell halves (one base + imm offsets) and stores channels 4h..4h+3.
__global__ __launch_bounds__(256, 4) void k_main(const float4* __restrict__ rec,
                                                 const float* __restrict__ table,
                                                 const unsigned* __restrict__ base,
                                                 float* __restrict__ out) {
    __shared__ float4 lds4[2560];   // 40960 B: [0,20480)=x-plane, [20480,40960)=x+1
    char* ldsb = (char*)lds4;
    const char* tb = (const char*)table;

    int g = blockIdx.x;
    int gx = g >> 5, gy2 = g & 31;
    int ybase = gy2 * 4;
    unsigned s = base[g], e = base[g + 1];

    unsigned offA = (unsigned)(gx * 128 + ybase) * 4096u;   // row (gx, ybase)
    unsigned offB = offA + 524288u;                          // +1 x-plane

    int t = (int)threadIdx.x;
    int lane = t & 63, wave = t >> 6;

    // 40 chunks of 1024 B; wave w stages chunks {w, w+4, ..., w+36}.
#pragma unroll
    for (int j = 0; j < 10; ++j) {
        int c = wave + j * 4;
        unsigned lo = (unsigned)c * 1024u;
        unsigned go = (c < 20) ? (offA + lo) : (offB + (lo - 20480u));
        go += (unsigned)lane * 16u;
        if (go > TBYTES - 16u) go = TBYTES - 16u;   // last bins' pad rows
        __builtin_amdgcn_global_load_lds(
            (const __attribute__((address_space(1))) void*)(tb + go),
            (__attribute__((address_space(3))) void*)(ldsb + lo), 16, 0, 0);
    }
    __syncthreads();
    if (e <= s) return;   // empty bin (after barrier)

    int p = lane >> 1, h = lane & 1;
    const float dmax = 127.0f, imax = 126.0f;
    const unsigned hoff = (unsigned)(h << 4);
    const unsigned last = e - 1u;

    unsigned myi = s + (unsigned)(wave * 32 + p);
    unsigned cnt = e - s;

#define PROC(rr, idx) { \
        if ((idx) < e) { \
            unsigned orig = __float_as_uint(rr.w); \
            float sx = fminf(fmaxf(rr.x, 0.0f), 1.0f) * dmax; \
            float sy = fminf(fmaxf(rr.y, 0.0f), 1.0f) * dmax; \
            float sz = fminf(fmaxf(rr.z, 0.0f), 1.0f) * dmax; \
            float fx0 = fminf(floorf(sx), imax); \
            float fy0 = fminf(floorf(sy), imax); \
            float fz0 = fminf(floorf(sz), imax); \
            int y0 = (int)fy0, z0 = (int)fz0; \
            float fx = sx - fx0, fy = sy - fy0, fz = sz - fz0; \
            float gxw = 1.0f - fx, gyw = 1.0f - fy, gzw = 1.0f - fz; \
            float wA0 = gxw * gyw * gzw, wA1 = gxw * gyw * fz; \
            float wB0 = gxw * fy  * gzw, wB1 = gxw * fy  * fz; \
            float wC0 = fx  * gyw * gzw, wC1 = fx  * gyw * fz; \
            float wD0 = fx  * fy  * gzw, wD1 = fx  * fy  * fz; \
            int dy = y0 - ybase; \
            unsigned a = (unsigned)(dy * 4096 + z0 * 32) + hoff; \
            float4 vA0 = *(const float4*)(ldsb + a); \
            float4 vA1 = *(const float4*)(ldsb + a + 32u); \
            float4 vB0 = *(const float4*)(ldsb + a + 4096u); \
            float4 vB1 = *(const float4*)(ldsb + a + 4128u); \
            float4 vC0 = *(const float4*)(ldsb + a + 20480u); \
            float4 vC1 = *(const float4*)(ldsb + a + 20512u); \
            float4 vD0 = *(const float4*)(ldsb + a + 24576u); \
            float4 vD1 = *(const float4*)(ldsb + a + 24608u); \
            float4 acc; \
            acc.x = wA0*vA0.x + wA1*vA1.x + wB0*vB0.x + wB1*vB1.x \
                  + wC0*vC0.x + wC1*vC1.x + wD0*vD0.x + wD1*vD1.x; \
            acc.y = wA0*vA0.y + wA1*vA1.y + wB0*vB0.y + wB1*vB1.y \
                  + wC0*vC0.y + wC1*vC1.y + wD0*vD0.y + wD1*vD1.y; \
            acc.z = wA0*vA0.z + wA1*vA1.z + wB0*vB0.z + wB1*vB1.z \
                  + wC0*vC0.z + wC1*vC1.z + wD0*vD0.z + wD1*vD1.z; \
            acc.w = wA0*vA0.w + wA1*vA1.w + wB0*vB0.w + wB1*vB1.w \
                  + wC0*vC0.w + wC1*vC1.w + wD0*vD0.w + wD1*vD1.w; \
            *reinterpret_cast<float4*>(out + (size_t)orig * CH + (h << 2)) = acc; \
        } }

    // 2-deep prefetch of this wave's records (pass stride = 128 points)
    float4 r0 = rec[min(myi, last)];
    float4 r1 = rec[min(myi + 128u, last)];

    for (unsigned c0 = 0; c0 < cnt; c0 += 256u) {
        float4 n0 = rec[min(myi + c0 + 256u, last)];
        float4 n1 = rec[min(myi + c0 + 384u, last)];
        PROC(r0, myi + c0 +   0u)
        PROC(r1, myi + c0 + 128u)
        r0 = n0; r1 = n1;
    }
#undef PROC
}

// Fallback (no workspace): direct gather.
__global__ __launch_bounds__(256) void k_naive(const float* __restrict__ un,
                                               const float* __restrict__ table,
                                               float* __restrict__ out, int batch) {
    int b = blockIdx.x * blockDim.x + threadIdx.x;
    if (b >= batch) return;
    float ux = un[3 * b], uy = un[3 * b + 1], uz = un[3 * b + 2];
    const float dmax = 127.0f, imax = 126.0f;
    float sx = fminf(fmaxf(ux, 0.0f), 1.0f) * dmax;
    float sy = fminf(fmaxf(uy, 0.0f), 1.0f) * dmax;
    float sz = fminf(fmaxf(uz, 0.0f), 1.0f) * dmax;
    float fx0 = fminf(floorf(sx), imax);
    float fy0 = fminf(floorf(sy), imax);
    float fz0 = fminf(floorf(sz), imax);
    int x0 = (int)fx0, y0 = (int)fy0, z0 = (int)fz0;
    float fx = sx - fx0, fy = sy - fy0, fz = sz - fz0;
    float wx[2] = {1.0f - fx, fx};
    float wy[2] = {1.0f - fy, fy};
    float wz0 = 1.0f - fz, wz1 = fz;
    float acc[CH];
#pragma unroll
    for (int c = 0; c < CH; ++c) acc[c] = 0.0f;
#pragma unroll
    for (int bx = 0; bx < 2; ++bx)
#pragma unroll
        for (int by = 0; by < 2; ++by) {
            const float* pp = table + ((size_t)((x0 + bx) * DIM + (y0 + by)) * DIM + z0) * CH;
            float wxy = wx[bx] * wy[by];
            float w0 = wxy * wz0, w1 = wxy * wz1;
            float4 a0 = *reinterpret_cast<const float4*>(pp + 0);
            float4 a1 = *reinterpret_cast<const float4*>(pp + 4);
            float4 b0 = *reinterpret_cast<const float4*>(pp + 8);
            float4 b1 = *reinterpret_cast<const float4*>(pp + 12);
            acc[0] += w0 * a0.x + w1 * b0.x;  acc[1] += w0 * a0.y + w1 * b0.y;
            acc[2] += w0 * a0.z + w1 * b0.z;  acc[3] += w0 * a0.w + w1 * b0.w;
            acc[4] += w0 * a1.x + w1 * b1.x;  acc[5] += w0 * a1.y + w1 * b1.y;
            acc[6] += w0 * a1.z + w1 * b1.z;  acc[7] += w0 * a1.w + w1 * b1.w;
        }
    float4* o = reinterpret_cast<float4*>(out + (size_t)b * CH);
    o[0] = make_float4(acc[0], acc[1], acc[2], acc[3]);
    o[1] = make_float4(acc[4], acc[5], acc[6], acc[7]);
}

extern "C" void kernel_launch(void* const* d_in, const int* in_sizes, int n_in,
                              void* d_out, int out_size, void* d_ws, size_t ws_size,
                              hipStream_t stream) {
    const float* un    = (const float*)d_in[0];
    const float* table = (const float*)d_in[1];
    float* out         = (float*)d_out;
    int batch = in_sizes[0] / 3;

    size_t need = (size_t)REC_OFF + (size_t)batch * 16;
    if (ws_size < need) {
        int grid = (batch + 255) / 256;
        k_naive<<<grid, 256, 0, stream>>>(un, table, out, batch);
        return;
    }

    unsigned* hist   = (unsigned*)d_ws;
    unsigned* cursor = (unsigned*)((char*)d_ws + CUR_OFF);
    unsigned* base   = (unsigned*)((char*)d_ws + BASE_OFF);
    float4*   rec    = (float4*)((char*)d_ws + REC_OFF);

    hipMemsetAsync(d_ws, 0, CUR_OFF, stream);            // zero hist only
    k_hist<<<512, 256, 0, stream>>>(un, hist, batch);
    k_scan<<<1, 1024, 0, stream>>>(hist, cursor, base);
    int nscat = (batch + CHUNK - 1) / CHUNK;
    k_scatter<<<nscat, 256, 0, stream>>>(un, cursor, rec, batch);
    k_main<<<NBIN, 256, 0, stream>>>(rec, table, base, out);
}

// Round 11
// 119.524 us; speedup vs baseline: 1.0058x; 1.0058x over previous
//
#include <hip/hip_runtime.h>

// Trilinear table lookup: (x, y/4)-bin counting sort -> per-bin LDS-staged,
// pair-cooperative gather, 8-wave blocks for full occupancy.
//
// unList: [B,3] f32 in [0,1]; table: [128,128,128,8] f32; out: [B,8] f32
//
// R10 evidence: all chain-level variants land at ~78us with Occupancy ~32%
// (12 waves/CU) -- latency-bound from too few waves, not from the chain.
// Fix: 512-thread (8-wave) blocks on the same 40KB slab => up to 32 waves/CU.

#define DIM 128
#define CH 8
#define NBIN 4064            // 127 x-cells * 32 y-groups (y0>>2)
#define TBYTES 67108864u     // 128^3 * 8 * 4
#define CHUNK 8192
#define PPT 32
// ws layout (bytes):
//   [0,     16384)  hist   (u32 x 4064, zeroed each call)
//   [16384, 32768)  cursor (u32 x 4064, rewritten by k_scan)
//   [32768, 49152)  base   (u32 x 4065, rewritten by k_scan)
//   [65536, ...  )  rec    (float4 x B : x,y,z,bits(orig))
#define CUR_OFF 16384
#define BASE_OFF 32768
#define REC_OFF 65536

__device__ __forceinline__ int key_of(float ux, float uy) {
    float sx = fminf(fmaxf(ux, 0.0f), 1.0f) * 127.0f;
    float sy = fminf(fmaxf(uy, 0.0f), 1.0f) * 127.0f;
    int x0 = (int)fminf(floorf(sx), 126.0f);
    int y0 = (int)fminf(floorf(sy), 126.0f);
    return x0 * 32 + (y0 >> 2);
}

__global__ __launch_bounds__(256) void k_hist(const float* __restrict__ un,
                                              unsigned* __restrict__ hist, int batch) {
    __shared__ unsigned lh[NBIN];
    for (int i = threadIdx.x; i < NBIN; i += 256) lh[i] = 0;
    __syncthreads();
    int stride = gridDim.x * blockDim.x;
    for (int i = blockIdx.x * blockDim.x + threadIdx.x; i < batch; i += stride)
        atomicAdd(&lh[key_of(un[3 * i], un[3 * i + 1])], 1u);
    __syncthreads();
    for (int i = threadIdx.x; i < NBIN; i += 256)
        if (lh[i]) atomicAdd(&hist[i], lh[i]);
}

// exclusive scan of 4064 bins -> cursor & base (+ base[NBIN] = total)
__global__ __launch_bounds__(1024) void k_scan(const unsigned* __restrict__ hist,
                                               unsigned* __restrict__ cursor,
                                               unsigned* __restrict__ base) {
    __shared__ unsigned s[1024];
    int t = threadIdx.x;
    int b0 = t * 4;
    unsigned loc[4], sum = 0;
#pragma unroll
    for (int j = 0; j < 4; ++j) {
        int k = b0 + j;
        unsigned h = (k < NBIN) ? hist[k] : 0u;
        loc[j] = sum;
        sum += h;
    }
    s[t] = sum;
    __syncthreads();
    for (int off = 1; off < 1024; off <<= 1) {
        unsigned v = (t >= off) ? s[t - off] : 0u;
        __syncthreads();
        s[t] += v;
        __syncthreads();
    }
    unsigned excl = s[t] - sum;
#pragma unroll
    for (int j = 0; j < 4; ++j) {
        int k = b0 + j;
        if (k < NBIN) { base[k] = excl + loc[j]; cursor[k] = excl + loc[j]; }
    }
    if (t == 1023) base[NBIN] = s[1023];
}

__global__ __launch_bounds__(256) void k_scatter(const float* __restrict__ un,
                                                 unsigned* __restrict__ cursor,
                                                 float4* __restrict__ rec, int batch) {
    __shared__ unsigned lh[NBIN];
    __shared__ unsigned lbase[NBIN];
    int t = threadIdx.x;
    for (int i = t; i < NBIN; i += 256) lh[i] = 0;
    __syncthreads();
    int start = blockIdx.x * CHUNK;
    unsigned kr[PPT];
#pragma unroll
    for (int j = 0; j < PPT; ++j) {
        int i = start + j * 256 + t;
        if (i < batch) {
            int k = key_of(un[3 * i], un[3 * i + 1]);
            unsigned r = atomicAdd(&lh[k], 1u);
            kr[j] = (unsigned)k | (r << 12);
        } else kr[j] = 0u;
    }
    __syncthreads();
    for (int i = t; i < NBIN; i += 256)
        lbase[i] = lh[i] ? atomicAdd(&cursor[i], lh[i]) : 0u;
    __syncthreads();
#pragma unroll
    for (int j = 0; j < PPT; ++j) {
        int i = start + j * 256 + t;
        if (i < batch) {
            unsigned k = kr[j] & 4095u, r = kr[j] >> 12;
            float ux = un[3 * i], uy = un[3 * i + 1], uz = un[3 * i + 2];
            rec[lbase[k] + r] = make_float4(ux, uy, uz, __uint_as_float((unsigned)i));
        }
    }
}

// One block (512 thr, 8 waves) per bin. Stage 40 KB (x-planes x0/x0+1, rows
// ybase..ybase+4) into LDS via global_load_lds DMA, then pair-cooperative
// gather: lane pair (2p,2p+1) owns point p; lane h = lane&1 reads all 8
// corner-cell halves (one base + imm offsets) and stores channels 4h..4h+3.
__global__ __launch_bounds__(512, 8) void k_main(const float4* __restrict__ rec,
                                                 const float* __restrict__ table,
                                                 const unsigned* __restrict__ base,
                                                 float* __restrict__ out) {
    __shared__ float4 lds4[2560];   // 40960 B: [0,20480)=x-plane, [20480,40960)=x+1
    char* ldsb = (char*)lds4;
    const char* tb = (const char*)table;

    int g = blockIdx.x;
    int gx = g >> 5, gy2 = g & 31;
    int ybase = gy2 * 4;
    unsigned s = base[g], e = base[g + 1];

    unsigned offA = (unsigned)(gx * 128 + ybase) * 4096u;   // row (gx, ybase)
    unsigned offB = offA + 524288u;                          // +1 x-plane

    int t = (int)threadIdx.x;
    int lane = t & 63, wave = t >> 6;    // wave 0..7

    // 40 chunks of 1024 B; wave w stages chunks {w, w+8, ..., w+32}.
#pragma unroll
    for (int j = 0; j < 5; ++j) {
        int c = wave + j * 8;
        unsigned lo = (unsigned)c * 1024u;
        unsigned go = (c < 20) ? (offA + lo) : (offB + (lo - 20480u));
        go += (unsigned)lane * 16u;
        if (go > TBYTES - 16u) go = TBYTES - 16u;   // last bins' pad rows
        __builtin_amdgcn_global_load_lds(
            (const __attribute__((address_space(1))) void*)(tb + go),
            (__attribute__((address_space(3))) void*)(ldsb + lo), 16, 0, 0);
    }
    __syncthreads();
    if (e <= s) return;   // empty bin (after barrier)

    int p = lane >> 1, h = lane & 1;
    const float dmax = 127.0f, imax = 126.0f;
    const unsigned hoff = (unsigned)(h << 4);
    const unsigned last = e - 1u;

    unsigned myi = s + (unsigned)(wave * 32 + p);
    unsigned cnt = e - s;

#define PROC(rr, idx) { \
        if ((idx) < e) { \
            unsigned orig = __float_as_uint(rr.w); \
            float sx = fminf(fmaxf(rr.x, 0.0f), 1.0f) * dmax; \
            float sy = fminf(fmaxf(rr.y, 0.0f), 1.0f) * dmax; \
            float sz = fminf(fmaxf(rr.z, 0.0f), 1.0f) * dmax; \
            float fx0 = fminf(floorf(sx), imax); \
            float fy0 = fminf(floorf(sy), imax); \
            float fz0 = fminf(floorf(sz), imax); \
            int y0 = (int)fy0, z0 = (int)fz0; \
            float fx = sx - fx0, fy = sy - fy0, fz = sz - fz0; \
            float gxw = 1.0f - fx, gyw = 1.0f - fy, gzw = 1.0f - fz; \
            float wA0 = gxw * gyw * gzw, wA1 = gxw * gyw * fz; \
            float wB0 = gxw * fy  * gzw, wB1 = gxw * fy  * fz; \
            float wC0 = fx  * gyw * gzw, wC1 = fx  * gyw * fz; \
            float wD0 = fx  * fy  * gzw, wD1 = fx  * fy  * fz; \
            int dy = y0 - ybase; \
            unsigned a = (unsigned)(dy * 4096 + z0 * 32) + hoff; \
            float4 vA0 = *(const float4*)(ldsb + a); \
            float4 vA1 = *(const float4*)(ldsb + a + 32u); \
            float4 vB0 = *(const float4*)(ldsb + a + 4096u); \
            float4 vB1 = *(const float4*)(ldsb + a + 4128u); \
            float4 vC0 = *(const float4*)(ldsb + a + 20480u); \
            float4 vC1 = *(const float4*)(ldsb + a + 20512u); \
            float4 vD0 = *(const float4*)(ldsb + a + 24576u); \
            float4 vD1 = *(const float4*)(ldsb + a + 24608u); \
            float4 acc; \
            acc.x = wA0*vA0.x + wA1*vA1.x + wB0*vB0.x + wB1*vB1.x \
                  + wC0*vC0.x + wC1*vC1.x + wD0*vD0.x + wD1*vD1.x; \
            acc.y = wA0*vA0.y + wA1*vA1.y + wB0*vB0.y + wB1*vB1.y \
                  + wC0*vC0.y + wC1*vC1.y + wD0*vD0.y + wD1*vD1.y; \
            acc.z = wA0*vA0.z + wA1*vA1.z + wB0*vB0.z + wB1*vB1.z \
                  + wC0*vC0.z + wC1*vC1.z + wD0*vD0.z + wD1*vD1.z; \
            acc.w = wA0*vA0.w + wA1*vA1.w + wB0*vB0.w + wB1*vB1.w \
                  + wC0*vC0.w + wC1*vC1.w + wD0*vD0.w + wD1*vD1.w; \
            *reinterpret_cast<float4*>(out + (size_t)orig * CH + (h << 2)) = acc; \
        } }

    // 1-deep rec prefetch; pass stride = 8 waves * 32 pts = 256
    float4 r0 = rec[min(myi, last)];
    for (unsigned c0 = 0; c0 < cnt; c0 += 256u) {
        float4 n0 = rec[min(myi + c0 + 256u, last)];
        PROC(r0, myi + c0)
        r0 = n0;
    }
#undef PROC
}

// Fallback (no workspace): direct gather.
__global__ __launch_bounds__(256) void k_naive(const float* __restrict__ un,
                                               const float* __restrict__ table,
                                               float* __restrict__ out, int batch) {
    int b = blockIdx.x * blockDim.x + threadIdx.x;
    if (b >= batch) return;
    float ux = un[3 * b], uy = un[3 * b + 1], uz = un[3 * b + 2];
    const float dmax = 127.0f, imax = 126.0f;
    float sx = fminf(fmaxf(ux, 0.0f), 1.0f) * dmax;
    float sy = fminf(fmaxf(uy, 0.0f), 1.0f) * dmax;
    float sz = fminf(fmaxf(uz, 0.0f), 1.0f) * dmax;
    float fx0 = fminf(floorf(sx), imax);
    float fy0 = fminf(floorf(sy), imax);
    float fz0 = fminf(floorf(sz), imax);
    int x0 = (int)fx0, y0 = (int)fy0, z0 = (int)fz0;
    float fx = sx - fx0, fy = sy - fy0, fz = sz - fz0;
    float wx[2] = {1.0f - fx, fx};
    float wy[2] = {1.0f - fy, fy};
    float wz0 = 1.0f - fz, wz1 = fz;
    float acc[CH];
#pragma unroll
    for (int c = 0; c < CH; ++c) acc[c] = 0.0f;
#pragma unroll
    for (int bx = 0; bx < 2; ++bx)
#pragma unroll
        for (int by = 0; by < 2; ++by) {
            const float* pp = table + ((size_t)((x0 + bx) * DIM + (y0 + by)) * DIM + z0) * CH;
            float wxy = wx[bx] * wy[by];
            float w0 = wxy * wz0, w1 = wxy * wz1;
            float4 a0 = *reinterpret_cast<const float4*>(pp + 0);
            float4 a1 = *reinterpret_cast<const float4*>(pp + 4);
            float4 b0 = *reinterpret_cast<const float4*>(pp + 8);
            float4 b1 = *reinterpret_cast<const float4*>(pp + 12);
            acc[0] += w0 * a0.x + w1 * b0.x;  acc[1] += w0 * a0.y + w1 * b0.y;
            acc[2] += w0 * a0.z + w1 * b0.z;  acc[3] += w0 * a0.w + w1 * b0.w;
            acc[4] += w0 * a1.x + w1 * b1.x;  acc[5] += w0 * a1.y + w1 * b1.y;
            acc[6] += w0 * a1.z + w1 * b1.z;  acc[7] += w0 * a1.w + w1 * b1.w;
        }
    float4* o = reinterpret_cast<float4*>(out + (size_t)b * CH);
    o[0] = make_float4(acc[0], acc[1], acc[2], acc[3]);
    o[1] = make_float4(acc[4], acc[5], acc[6], acc[7]);
}

extern "C" void kernel_launch(void* const* d_in, const int* in_sizes, int n_in,
                              void* d_out, int out_size, void* d_ws, size_t ws_size,
                              hipStream_t stream) {
    const float* un    = (const float*)d_in[0];
    const float* table = (const float*)d_in[1];
    float* out         = (float*)d_out;
    int batch = in_sizes[0] / 3;

    size_t need = (size_t)REC_OFF + (size_t)batch * 16;
    if (ws_size < need) {
        int grid = (batch + 255) / 256;
        k_naive<<<grid, 256, 0, stream>>>(un, table, out, batch);
        return;
    }

    unsigned* hist   = (unsigned*)d_ws;
    unsigned* cursor = (unsigned*)((char*)d_ws + CUR_OFF);
    unsigned* base   = (unsigned*)((char*)d_ws + BASE_OFF);
    float4*   rec    = (float4*)((char*)d_ws + REC_OFF);

    hipMemsetAsync(d_ws, 0, CUR_OFF, stream);            // zero hist only
    k_hist<<<512, 256, 0, stream>>>(un, hist, batch);
    k_scan<<<1, 1024, 0, stream>>>(hist, cursor, base);
    int nscat = (batch + CHUNK - 1) / CHUNK;
    k_scatter<<<nscat, 256, 0, stream>>>(un, cursor, rec, batch);
    k_main<<<NBIN, 512, 0, stream>>>(rec, table, base, out);
}

// Round 12
// 108.784 us; speedup vs baseline: 1.1051x; 1.0987x over previous
//
#include <hip/hip_runtime.h>

// Trilinear table lookup: (x/2, y/4)-bin counting sort -> per-bin LDS-staged,
// pair-cooperative gather. 8-byte quantized records.
//
// unList: [B,3] f32 in [0,1]; table: [128,128,128,8] f32; out: [B,8] f32
//
// R11 evidence: time is set by aggregate L2/fabric traffic (all ILP/TLP
// variants null; only traffic cuts ever moved time). This round cuts traffic:
// bins of 2 x-cells x 4 y-cells stage 3 planes x 5 rows = 60 KB for ~1024
// points (staging 166->126 MB), and records shrink 16->8 B (quantized fracs,
// added err ~1e-3 << 2e-2 threshold).

#define DIM 128
#define CH 8
#define NBIN 2048            // 64 x-groups (x0>>1) * 32 y-groups (y0>>2)
#define TBYTES 67108864u     // 128^3 * 8 * 4
#define CHUNK 8192
#define PPT 32
#define SLAB 61440           // 3 planes * 5 rows * 4096 B
// ws layout (bytes):
//   [0,      8192)  hist   (u32 x 2048, zeroed each call)
//   [8192,  16384)  cursor (u32 x 2048, rewritten by k_scan)
//   [16384, 24584)  base   (u32 x 2049, rewritten by k_scan)
//   [32768, ...  )  rec    (uint2 x B, 8 B each)
#define CUR_OFF 8192
#define BASE_OFF 16384
#define REC_OFF 32768

__device__ __forceinline__ int key_of(float ux, float uy) {
    float sx = fminf(fmaxf(ux, 0.0f), 1.0f) * 127.0f;
    float sy = fminf(fmaxf(uy, 0.0f), 1.0f) * 127.0f;
    int x0 = (int)fminf(floorf(sx), 126.0f);
    int y0 = (int)fminf(floorf(sy), 126.0f);
    return (x0 >> 1) * 32 + (y0 >> 2);
}

__global__ __launch_bounds__(256) void k_hist(const float* __restrict__ un,
                                              unsigned* __restrict__ hist, int batch) {
    __shared__ unsigned lh[NBIN];
    for (int i = threadIdx.x; i < NBIN; i += 256) lh[i] = 0;
    __syncthreads();
    int stride = gridDim.x * blockDim.x;
    for (int i = blockIdx.x * blockDim.x + threadIdx.x; i < batch; i += stride)
        atomicAdd(&lh[key_of(un[3 * i], un[3 * i + 1])], 1u);
    __syncthreads();
    for (int i = threadIdx.x; i < NBIN; i += 256)
        if (lh[i]) atomicAdd(&hist[i], lh[i]);
}

// exclusive scan of 2048 bins -> cursor & base (+ base[NBIN] = total)
__global__ __launch_bounds__(1024) void k_scan(const unsigned* __restrict__ hist,
                                               unsigned* __restrict__ cursor,
                                               unsigned* __restrict__ base) {
    __shared__ unsigned s[1024];
    int t = threadIdx.x;
    unsigned h0 = hist[t * 2], h1 = hist[t * 2 + 1];
    s[t] = h0 + h1;
    __syncthreads();
    for (int off = 1; off < 1024; off <<= 1) {
        unsigned v = (t >= off) ? s[t - off] : 0u;
        __syncthreads();
        s[t] += v;
        __syncthreads();
    }
    unsigned excl = s[t] - (h0 + h1);
    base[t * 2] = excl;           cursor[t * 2] = excl;
    base[t * 2 + 1] = excl + h0;  cursor[t * 2 + 1] = excl + h0;
    if (t == 1023) base[NBIN] = s[1023];
}

__global__ __launch_bounds__(256) void k_scatter(const float* __restrict__ un,
                                                 unsigned* __restrict__ cursor,
                                                 uint2* __restrict__ rec, int batch) {
    __shared__ unsigned lh[NBIN];
    __shared__ unsigned lbase[NBIN];
    int t = threadIdx.x;
    for (int i = t; i < NBIN; i += 256) lh[i] = 0;
    __syncthreads();
    int start = blockIdx.x * CHUNK;
    unsigned kr[PPT];
#pragma unroll
    for (int j = 0; j < PPT; ++j) {
        int i = start + j * 256 + t;
        if (i < batch) {
            int k = key_of(un[3 * i], un[3 * i + 1]);
            unsigned r = atomicAdd(&lh[k], 1u);
            kr[j] = (unsigned)k | (r << 12);
        } else kr[j] = 0u;
    }
    __syncthreads();
    for (int i = t; i < NBIN; i += 256)
        lbase[i] = lh[i] ? atomicAdd(&cursor[i], lh[i]) : 0u;
    __syncthreads();
#pragma unroll
    for (int j = 0; j < PPT; ++j) {
        int i = start + j * 256 + t;
        if (i < batch) {
            unsigned k = kr[j] & 4095u, r = kr[j] >> 12;
            float ux = un[3 * i], uy = un[3 * i + 1], uz = un[3 * i + 2];
            float sx = fminf(fmaxf(ux, 0.0f), 1.0f) * 127.0f;
            float sy = fminf(fmaxf(uy, 0.0f), 1.0f) * 127.0f;
            float sz = fminf(fmaxf(uz, 0.0f), 1.0f) * 127.0f;
            float fx0 = fminf(floorf(sx), 126.0f);
            float fy0 = fminf(floorf(sy), 126.0f);
            float fz0 = fminf(floorf(sz), 126.0f);
            int x0 = (int)fx0, y0 = (int)fy0, z0 = (int)fz0;
            unsigned qx = (unsigned)((sx - fx0) * 2047.0f + 0.5f);
            unsigned qy = (unsigned)((sy - fy0) * 2047.0f + 0.5f);
            unsigned qz = (unsigned)((sz - fz0) * 1023.0f + 0.5f);
            unsigned dx = (unsigned)(x0 & 1);       // x0 - 2*(x0>>1)
            unsigned dy = (unsigned)(y0 & 3);       // y0 - 4*(y0>>2)
            uint2 rr;
            rr.x = (unsigned)i | (dx << 21) | (dy << 22) | ((unsigned)z0 << 24);
            rr.y = qx | (qy << 11) | (qz << 22);
            rec[lbase[k] + r] = rr;
        }
    }
}

// One block (512 thr, 8 waves) per bin. Stage 60 KB (planes 2X..2X+2, rows
// 4Y..4Y+4) into LDS via global_load_lds DMA, then pair-cooperative gather:
// lane pair (2p,2p+1) owns a point; lane h reads the 8 corner-cell halves
// (one base + imm offsets) and stores channels 4h..4h+3.
__global__ __launch_bounds__(512, 4) void k_main(const uint2* __restrict__ rec,
                                                 const float* __restrict__ table,
                                                 const unsigned* __restrict__ base,
                                                 float* __restrict__ out) {
    __shared__ float4 lds4[SLAB / 16];
    char* ldsb = (char*)lds4;
    const char* tb = (const char*)table;

    // XCD swizzle: XCD x gets a contiguous range of bins (2048 % 8 == 0)
    int pb = (int)blockIdx.x;
    int g = (pb & 7) * 256 + (pb >> 3);
    int X = g >> 5, Y = g & 31;
    unsigned s = base[g], e = base[g + 1];

    int t = (int)threadIdx.x;
    int lane = t & 63, wave = t >> 6;    // wave 0..7

    // 60 chunks of 1024 B; wave w stages chunks {w, w+8, ...} < 60.
#pragma unroll
    for (int j = 0; j < 8; ++j) {
        int c = wave + j * 8;
        if (c < 60) {
            int pr = c >> 2, q4 = c & 3;
            int p = (pr * 13) >> 6;           // pr/5 for pr in 0..14
            int r = pr - p * 5;
            int gp = 2 * X + p;  if (gp > 127) gp = 127;
            int gr = 4 * Y + r;  if (gr > 127) gr = 127;
            unsigned go = (unsigned)((gp * 128 + gr) * 4096 + q4 * 1024)
                        + (unsigned)lane * 16u;
            __builtin_amdgcn_global_load_lds(
                (const __attribute__((address_space(1))) void*)(tb + go),
                (__attribute__((address_space(3))) void*)(ldsb + (unsigned)c * 1024u),
                16, 0, 0);
        }
    }
    __syncthreads();
    if (e <= s) return;   // empty bin (after barrier)

    int p = lane >> 1, h = lane & 1;
    const unsigned hoff = (unsigned)(h << 4);
    const unsigned last = e - 1u;
    const float rs11 = 1.0f / 2047.0f, rs10 = 1.0f / 1023.0f;

    unsigned myi = s + (unsigned)(wave * 32 + p);
    unsigned cnt = e - s;

#define PROC(rr, idx) { \
        if ((idx) < e) { \
            unsigned orig = rr.x & 0x1FFFFFu; \
            unsigned dx = (rr.x >> 21) & 1u; \
            unsigned dy = (rr.x >> 22) & 3u; \
            unsigned z0 = (rr.x >> 24) & 0x7Fu; \
            float fx = (float)(rr.y & 0x7FFu) * rs11; \
            float fy = (float)((rr.y >> 11) & 0x7FFu) * rs11; \
            float fz = (float)(rr.y >> 22) * rs10; \
            float gxw = 1.0f - fx, gyw = 1.0f - fy, gzw = 1.0f - fz; \
            float wA0 = gxw * gyw * gzw, wA1 = gxw * gyw * fz; \
            float wB0 = gxw * fy  * gzw, wB1 = gxw * fy  * fz; \
            float wC0 = fx  * gyw * gzw, wC1 = fx  * gyw * fz; \
            float wD0 = fx  * fy  * gzw, wD1 = fx  * fy  * fz; \
            unsigned a = (dx * 5u + dy) * 4096u + z0 * 32u + hoff; \
            float4 vA0 = *(const float4*)(ldsb + a); \
            float4 vA1 = *(const float4*)(ldsb + a + 32u); \
            float4 vB0 = *(const float4*)(ldsb + a + 4096u); \
            float4 vB1 = *(const float4*)(ldsb + a + 4128u); \
            float4 vC0 = *(const float4*)(ldsb + a + 20480u); \
            float4 vC1 = *(const float4*)(ldsb + a + 20512u); \
            float4 vD0 = *(const float4*)(ldsb + a + 24576u); \
            float4 vD1 = *(const float4*)(ldsb + a + 24608u); \
            float4 acc; \
            acc.x = wA0*vA0.x + wA1*vA1.x + wB0*vB0.x + wB1*vB1.x \
                  + wC0*vC0.x + wC1*vC1.x + wD0*vD0.x + wD1*vD1.x; \
            acc.y = wA0*vA0.y + wA1*vA1.y + wB0*vB0.y + wB1*vB1.y \
                  + wC0*vC0.y + wC1*vC1.y + wD0*vD0.y + wD1*vD1.y; \
            acc.z = wA0*vA0.z + wA1*vA1.z + wB0*vB0.z + wB1*vB1.z \
                  + wC0*vC0.z + wC1*vC1.z + wD0*vD0.z + wD1*vD1.z; \
            acc.w = wA0*vA0.w + wA1*vA1.w + wB0*vB0.w + wB1*vB1.w \
                  + wC0*vC0.w + wC1*vC1.w + wD0*vD0.w + wD1*vD1.w; \
            *reinterpret_cast<float4*>(out + (size_t)orig * CH + (h << 2)) = acc; \
        } }

    // 1-deep rec prefetch; pass stride = 8 waves * 32 pts = 256
    uint2 r0 = rec[min(myi, last)];
    for (unsigned c0 = 0; c0 < cnt; c0 += 256u) {
        uint2 n0 = rec[min(myi + c0 + 256u, last)];
        PROC(r0, myi + c0)
        r0 = n0;
    }
#undef PROC
}

// Fallback (no workspace): direct gather.
__global__ __launch_bounds__(256) void k_naive(const float* __restrict__ un,
                                               const float* __restrict__ table,
                                               float* __restrict__ out, int batch) {
    int b = blockIdx.x * blockDim.x + threadIdx.x;
    if (b >= batch) return;
    float ux = un[3 * b], uy = un[3 * b + 1], uz = un[3 * b + 2];
    const float dmax = 127.0f, imax = 126.0f;
    float sx = fminf(fmaxf(ux, 0.0f), 1.0f) * dmax;
    float sy = fminf(fmaxf(uy, 0.0f), 1.0f) * dmax;
    float sz = fminf(fmaxf(uz, 0.0f), 1.0f) * dmax;
    float fx0 = fminf(floorf(sx), imax);
    float fy0 = fminf(floorf(sy), imax);
    float fz0 = fminf(floorf(sz), imax);
    int x0 = (int)fx0, y0 = (int)fy0, z0 = (int)fz0;
    float fx = sx - fx0, fy = sy - fy0, fz = sz - fz0;
    float wx[2] = {1.0f - fx, fx};
    float wy[2] = {1.0f - fy, fy};
    float wz0 = 1.0f - fz, wz1 = fz;
    float acc[CH];
#pragma unroll
    for (int c = 0; c < CH; ++c) acc[c] = 0.0f;
#pragma unroll
    for (int bx = 0; bx < 2; ++bx)
#pragma unroll
        for (int by = 0; by < 2; ++by) {
            const float* pp = table + ((size_t)((x0 + bx) * DIM + (y0 + by)) * DIM + z0) * CH;
            float wxy = wx[bx] * wy[by];
            float w0 = wxy * wz0, w1 = wxy * wz1;
            float4 a0 = *reinterpret_cast<const float4*>(pp + 0);
            float4 a1 = *reinterpret_cast<const float4*>(pp + 4);
            float4 b0 = *reinterpret_cast<const float4*>(pp + 8);
            float4 b1 = *reinterpret_cast<const float4*>(pp + 12);
            acc[0] += w0 * a0.x + w1 * b0.x;  acc[1] += w0 * a0.y + w1 * b0.y;
            acc[2] += w0 * a0.z + w1 * b0.z;  acc[3] += w0 * a0.w + w1 * b0.w;
            acc[4] += w0 * a1.x + w1 * b1.x;  acc[5] += w0 * a1.y + w1 * b1.y;
            acc[6] += w0 * a1.z + w1 * b1.z;  acc[7] += w0 * a1.w + w1 * b1.w;
        }
    float4* o = reinterpret_cast<float4*>(out + (size_t)b * CH);
    o[0] = make_float4(acc[0], acc[1], acc[2], acc[3]);
    o[1] = make_float4(acc[4], acc[5], acc[6], acc[7]);
}

extern "C" void kernel_launch(void* const* d_in, const int* in_sizes, int n_in,
                              void* d_out, int out_size, void* d_ws, size_t ws_size,
                              hipStream_t stream) {
    const float* un    = (const float*)d_in[0];
    const float* table = (const float*)d_in[1];
    float* out         = (float*)d_out;
    int batch = in_sizes[0] / 3;

    size_t need = (size_t)REC_OFF + (size_t)batch * 8;
    if (ws_size < need || batch > (1 << 21)) {
        int grid = (batch + 255) / 256;
        k_naive<<<grid, 256, 0, stream>>>(un, table, out, batch);
        return;
    }

    unsigned* hist   = (unsigned*)d_ws;
    unsigned* cursor = (unsigned*)((char*)d_ws + CUR_OFF);
    unsigned* base   = (unsigned*)((char*)d_ws + BASE_OFF);
    uint2*    rec    = (uint2*)((char*)d_ws + REC_OFF);

    hipMemsetAsync(d_ws, 0, CUR_OFF, stream);            // zero hist only
    k_hist<<<512, 256, 0, stream>>>(un, hist, batch);
    k_scan<<<1, 1024, 0, stream>>>(hist, cursor, base);
    int nscat = (batch + CHUNK - 1) / CHUNK;
    k_scatter<<<nscat, 256, 0, stream>>>(un, cursor, rec, batch);
    k_main<<<NBIN, 512, 0, stream>>>(rec, table, base, out);
}